// Round 4
// baseline (88.428 us; speedup 1.0000x reference)
//
#include <hip/hip_runtime.h>

// VQ-VAE codebook forward, B=8,C=64,H=64,W=64, K=8192, D=64.
// Reference quirk: the cross term is a SCALAR, so argmin over k is independent
// of n: idx[n] == argmin_k |book_k|^2 for all n.
// Outputs (concatenated float32):
//   [0 .. 2097151]      z_q permuted to [B,W,C,H]: out[b,w,c,h] = e[w], e=book[kmin]
//   [2097152..2129919]  idx: 32768 x float(kmin)
//   [2129920]           loss = 1.25 * mean((e[w] - in[b,c,h,w])^2)
//
// R4: 2 graph nodes. k3 folded into k2 via last-block-done (512 spread
// done-counter atomics -- NOT R1's 4608 contended RMWs; partials via
// device-scope release stores / relaxed loads to distinct addresses).
// k1 zero-inits the done counter (kernel boundary = full fence, no memset node).
// Fixed floor outside our control: ~45 us of harness d_ws/d_out re-poison
// (256 MB fill at 81% HBM peak visible in profile).

#define NTOT    2097152   // 8*64*64*64
#define NIDX    32768
#define K_ROWS  8192
#define K1_BLK  512       // 16 rows/block, 16 lanes (one float4) per row
#define K2_BLK  512
#define K2_ITER 4         // 524288 float4 tasks / (512*256)

// ws layout: [0 .. 4095]    512 x u64 per-block argmin keys
//            [4096 .. 6143] 512 x float loss partials
//            [6144]         u32 done counter

__global__ __launch_bounds__(256) void k1_argmin(const float* __restrict__ book,
                                                 unsigned long long* __restrict__ ws_keys,
                                                 unsigned int* __restrict__ ws_done) {
    const int t   = threadIdx.x;
    const int rIn = t >> 4;                       // row within block, 0..15
    const int c4  = t & 15;                       // float4 column
    const int row = blockIdx.x * 16 + rIn;

    if (blockIdx.x == 0 && t == 0) *ws_done = 0;  // visible to k2 via kernel boundary

    const float4 v = ((const float4*)book)[row * 16 + c4];   // fully coalesced
    float s = v.x * v.x + v.y * v.y + v.z * v.z + v.w * v.w;
    // reduce across the 16 contiguous lanes of this row
    s += __shfl_down(s, 8, 16);
    s += __shfl_down(s, 4, 16);
    s += __shfl_down(s, 2, 16);
    s += __shfl_down(s, 1, 16);

    __shared__ unsigned long long keys[16];
    if (c4 == 0) {
        // positive-float bits are monotone as uint -> u64 min gives min norm,
        // ties broken to LOWEST row (jnp.argmin semantics).
        keys[rIn] = ((unsigned long long)__float_as_uint(s) << 32)
                  | (unsigned int)row;
    }
    __syncthreads();
    if (t == 0) {
        unsigned long long k = keys[0];
        #pragma unroll
        for (int i = 1; i < 16; ++i) k = keys[i] < k ? keys[i] : k;
        ws_keys[blockIdx.x] = k;                  // plain store, no atomic
    }
}

__global__ __launch_bounds__(256) void k2_main(const float* __restrict__ in,
                                               const float* __restrict__ book,
                                               float* __restrict__ out,
                                               const unsigned long long* __restrict__ ws_keys,
                                               float* __restrict__ ws_part,
                                               unsigned int* __restrict__ ws_done) {
    const int lane = threadIdx.x & 63, wid = threadIdx.x >> 6;

    // ---- resolve kmin: wave 0 reduces the 512 L2-hot keys, LDS-broadcast ----
    __shared__ unsigned long long skey;
    if (wid == 0) {
        unsigned long long key = ~0ULL;
        #pragma unroll
        for (int j = 0; j < K1_BLK / 64; ++j) {
            unsigned long long o = ws_keys[lane + j * 64];
            key = o < key ? o : key;
        }
        #pragma unroll
        for (int off = 32; off > 0; off >>= 1) {
            unsigned long long o = __shfl_down(key, off, 64);
            key = o < key ? o : key;
        }
        if (lane == 0) skey = key;
    }
    __syncthreads();
    const int kmin = (int)(skey & 0xFFFFFFFFu);
    const float* __restrict__ e = book + kmin * 64;   // L2-hot broadcast row

    const int tid = blockIdx.x * 256 + threadIdx.x;   // 131072 threads

    // ---- idx output: 32768 floats == float(kmin) (blocks 0..31) ----
    if (tid < NIDX / 4) {
        const float kf = (float)kmin;
        ((float4*)(out + NTOT))[tid] = make_float4(kf, kf, kf, kf);
    }

    // ---- z_q out [B,W,C,H] + fused loss over in [B,C,H,W], 4 float4/thread ----
    float part = 0.f;
    #pragma unroll
    for (int it = 0; it < K2_ITER; ++it) {
        const int i = tid + it * (K2_BLK * 256);       // float4 index
        // z_q: float offset o=4i -> value e[(o>>12)&63]
        const float ev = e[(i >> 10) & 63];
        ((float4*)out)[i] = make_float4(ev, ev, ev, ev);
        // loss: in float4 i covers w = (4i&63)..+3
        const float4 z  = ((const float4*)in)[i];
        const float4 ef = ((const float4*)e)[i & 15];
        const float d0 = z.x - ef.x, d1 = z.y - ef.y;
        const float d2 = z.z - ef.z, d3 = z.w - ef.w;
        part += d0 * d0 + d1 * d1 + d2 * d2 + d3 * d3;
    }
    #pragma unroll
    for (int off = 32; off > 0; off >>= 1) part += __shfl_down(part, off, 64);

    __shared__ float sp[4];
    __shared__ bool amLast;
    if (lane == 0) sp[wid] = part;
    __syncthreads();
    if (threadIdx.x == 0) {
        const float bs = sp[0] + sp[1] + sp[2] + sp[3];
        // device-scope release store of this block's partial, then signal.
        __hip_atomic_store(&ws_part[blockIdx.x], bs,
                           __ATOMIC_RELEASE, __HIP_MEMORY_SCOPE_AGENT);
        const unsigned int old = __hip_atomic_fetch_add(ws_done, 1u,
                                   __ATOMIC_ACQ_REL, __HIP_MEMORY_SCOPE_AGENT);
        amLast = (old == (unsigned int)(K2_BLK - 1));
    }
    __syncthreads();
    if (amLast && wid == 0) {
        // last block: sum 512 partials (distinct addresses, agent-scope loads)
        float s = 0.f;
        #pragma unroll
        for (int j = 0; j < K2_BLK / 64; ++j)
            s += __hip_atomic_load(&ws_part[lane + j * 64],
                                   __ATOMIC_RELAXED, __HIP_MEMORY_SCOPE_AGENT);
        #pragma unroll
        for (int off = 32; off > 0; off >>= 1) s += __shfl_down(s, off, 64);
        if (lane == 0)
            out[NTOT + NIDX] = s * (1.25f / (float)NTOT);
    }
}

extern "C" void kernel_launch(void* const* d_in, const int* in_sizes, int n_in,
                              void* d_out, int out_size, void* d_ws, size_t ws_size,
                              hipStream_t stream) {
    const float* in   = (const float*)d_in[0];   // [8,64,64,64] fp32
    const float* book = (const float*)d_in[1];   // [8192,64] fp32
    float* out = (float*)d_out;

    unsigned long long* ws_keys = (unsigned long long*)d_ws;
    float*              ws_part = (float*)((char*)d_ws + 4096);
    unsigned int*       ws_done = (unsigned int*)((char*)d_ws + 6144);

    k1_argmin<<<K1_BLK, 256, 0, stream>>>(book, ws_keys, ws_done);
    k2_main<<<K2_BLK, 256, 0, stream>>>(in, book, out, ws_keys, ws_part, ws_done);
}

// Round 5
// 69.864 us; speedup vs baseline: 1.2657x; 1.2657x over previous
//
#include <hip/hip_runtime.h>

// VQ-VAE codebook forward, B=8,C=64,H=64,W=64, K=8192, D=64.
// Reference quirk: the cross term is a SCALAR, so argmin over k is independent
// of n: idx[n] == argmin_k |book_k|^2 for all n.
// Outputs (concatenated float32):
//   [0 .. 2097151]      z_q permuted to [B,W,C,H]: out[b,w,c,h] = e[w], e=book[kmin]
//   [2097152..2129919]  idx: 32768 x float(kmin)
//   [2129920]           loss = 1.25 * mean((e[w] - in[b,c,h,w])^2)
//
// R5: 2 graph nodes, ZERO atomics (R1/R4 lesson: same-address device RMWs
// cost ~40-50ns each serialized + ordering traffic).
// Loss restructured: sum(e[w]-x)^2 = T - 2*sum_w e_w*S_w + 32768*sum_w e_w^2
// with T = sum x^2, S_w = per-w column sums of input -- both kmin-independent,
// so kernel A computes them alongside the book argmin (reads overlap).
// Kernel B writes z_q/idx; its statically-last block folds the closed-form loss.
// Fixed floor outside our control: ~45 us harness d_ws/d_out re-poison.

#define NTOT    2097152   // 8*64*64*64
#define NIDX    32768
#define NBLK    512       // both kernels: 512 blocks x 256 threads

// ws layout: [0    .. 4095]   512 x u64 per-block argmin keys
//            [4096 .. 6143]   512 x float T partials
//            [8192 .. 139263] 512 x 64 float S_w partials (block-major)

__global__ __launch_bounds__(256) void kA_stats(const float* __restrict__ in,
                                                const float* __restrict__ book,
                                                unsigned long long* __restrict__ ws_keys,
                                                float* __restrict__ ws_T,
                                                float4* __restrict__ ws_sw) {
    const int t    = threadIdx.x;
    const int lane = t & 63, wid = t >> 6;

    __shared__ unsigned long long keys[16];
    __shared__ float4 swv[4][16];
    __shared__ float  twv[4];

    // ---- book argmin: 16 rows/block, 16 lanes (one float4) per row ----
    {
        const int rIn = t >> 4, c4 = t & 15;
        const int row = blockIdx.x * 16 + rIn;
        const float4 v = ((const float4*)book)[row * 16 + c4];
        float s = v.x * v.x + v.y * v.y + v.z * v.z + v.w * v.w;
        s += __shfl_down(s, 8, 16);
        s += __shfl_down(s, 4, 16);
        s += __shfl_down(s, 2, 16);
        s += __shfl_down(s, 1, 16);
        if (c4 == 0) {
            // positive-float bits monotone as uint -> u64 min = min norm,
            // ties to LOWEST row (jnp.argmin semantics).
            keys[rIn] = ((unsigned long long)__float_as_uint(s) << 32)
                      | (unsigned int)row;
        }
    }

    // ---- input stats: T = sum x^2, S_w = column sums (w = flat&63) ----
    // thread's w-quad is constant: (tid + it*131072) & 15 == t & 15.
    const int tid = blockIdx.x * 256 + t;
    float4 cs = make_float4(0.f, 0.f, 0.f, 0.f);
    float  tp = 0.f;
    #pragma unroll
    for (int it = 0; it < 4; ++it) {
        const float4 z = ((const float4*)in)[tid + it * (NBLK * 256)];
        cs.x += z.x; cs.y += z.y; cs.z += z.z; cs.w += z.w;
        tp += z.x * z.x + z.y * z.y + z.z * z.z + z.w * z.w;
    }
    // reduce colsums over lanes congruent mod 16 (lanes l, l+16, l+32, l+48)
    #pragma unroll
    for (int off = 32; off >= 16; off >>= 1) {
        cs.x += __shfl_down(cs.x, off, 64);
        cs.y += __shfl_down(cs.y, off, 64);
        cs.z += __shfl_down(cs.z, off, 64);
        cs.w += __shfl_down(cs.w, off, 64);
    }
    // full wave reduce for T
    #pragma unroll
    for (int off = 32; off > 0; off >>= 1) tp += __shfl_down(tp, off, 64);

    if (lane < 16) swv[wid][lane] = cs;
    if (lane == 0) twv[wid] = tp;
    __syncthreads();

    if (t < 16) {   // per-block S_w quad (w = 4t..4t+3)
        const float4 a = swv[0][t], b = swv[1][t], c = swv[2][t], d = swv[3][t];
        ws_sw[blockIdx.x * 16 + t] =
            make_float4(a.x + b.x + c.x + d.x, a.y + b.y + c.y + d.y,
                        a.z + b.z + c.z + d.z, a.w + b.w + c.w + d.w);
    }
    if (t == 0) {
        ws_T[blockIdx.x] = twv[0] + twv[1] + twv[2] + twv[3];
        unsigned long long k = keys[0];
        #pragma unroll
        for (int i = 1; i < 16; ++i) k = keys[i] < k ? keys[i] : k;
        ws_keys[blockIdx.x] = k;              // plain store
    }
}

__global__ __launch_bounds__(256) void kB_write(const float* __restrict__ book,
                                                float* __restrict__ out,
                                                const unsigned long long* __restrict__ ws_keys,
                                                const float* __restrict__ ws_T,
                                                const float* __restrict__ ws_sw_f) {
    const int lane = threadIdx.x & 63, wid = threadIdx.x >> 6;

    // ---- resolve kmin: wave 0 reduces the 512 L2-hot keys, LDS-broadcast ----
    __shared__ unsigned long long skey;
    if (wid == 0) {
        unsigned long long key = ~0ULL;
        #pragma unroll
        for (int j = 0; j < NBLK / 64; ++j) {
            const unsigned long long o = ws_keys[lane + j * 64];
            key = o < key ? o : key;
        }
        #pragma unroll
        for (int off = 32; off > 0; off >>= 1) {
            const unsigned long long o = __shfl_down(key, off, 64);
            key = o < key ? o : key;
        }
        if (lane == 0) skey = key;
    }
    __syncthreads();
    const int kmin = (int)(skey & 0xFFFFFFFFu);
    const float* __restrict__ e = book + kmin * 64;   // L2-hot row

    const int tid = blockIdx.x * 256 + threadIdx.x;

    // ---- idx output: 32768 floats == float(kmin) (blocks 0..31) ----
    if (tid < NIDX / 4) {
        const float kf = (float)kmin;
        ((float4*)(out + NTOT))[tid] = make_float4(kf, kf, kf, kf);
    }

    // ---- z_q out [B,W,C,H]: float offset o=4i -> e[(o>>12)&63] ----
    #pragma unroll
    for (int it = 0; it < 4; ++it) {
        const int i = tid + it * (NBLK * 256);
        const float ev = e[(i >> 10) & 63];
        ((float4*)out)[i] = make_float4(ev, ev, ev, ev);
    }

    // ---- statically-last block: fold the closed-form loss ----
    if (blockIdx.x == NBLK - 1) {
        __shared__ float swv[4][64];
        __shared__ float tpv[4];
        // S_w totals: wave `wid` sums blocks [wid*128, wid*128+128), lane = w
        float s = 0.f;
        for (int j = 0; j < NBLK / 4; ++j)
            s += ws_sw_f[(wid * (NBLK / 4) + j) * 64 + lane];   // coalesced per wave
        swv[wid][lane] = s;
        // T total: 512 partials, 2 per thread, wave reduce
        float tq = ws_T[threadIdx.x] + ws_T[threadIdx.x + 256];
        #pragma unroll
        for (int off = 32; off > 0; off >>= 1) tq += __shfl_down(tq, off, 64);
        if (lane == 0) tpv[wid] = tq;
        __syncthreads();
        if (threadIdx.x < 64) {
            const int w = threadIdx.x;
            const float sw = swv[0][w] + swv[1][w] + swv[2][w] + swv[3][w];
            const float ew = e[w];
            float cross = ew * sw;
            float e2    = ew * ew;
            #pragma unroll
            for (int off = 32; off > 0; off >>= 1) {
                cross += __shfl_down(cross, off, 64);
                e2    += __shfl_down(e2,    off, 64);
            }
            if (w == 0) {
                const float T = tpv[0] + tpv[1] + tpv[2] + tpv[3];
                const float lsum = T - 2.f * cross + (float)(NTOT / 64) * e2;
                out[NTOT + NIDX] = lsum * (1.25f / (float)NTOT);
            }
        }
    }
}

extern "C" void kernel_launch(void* const* d_in, const int* in_sizes, int n_in,
                              void* d_out, int out_size, void* d_ws, size_t ws_size,
                              hipStream_t stream) {
    const float* in   = (const float*)d_in[0];   // [8,64,64,64] fp32
    const float* book = (const float*)d_in[1];   // [8192,64] fp32
    float* out = (float*)d_out;

    unsigned long long* ws_keys = (unsigned long long*)d_ws;
    float*              ws_T    = (float*)((char*)d_ws + 4096);
    float4*             ws_sw   = (float4*)((char*)d_ws + 8192);
    const float*        ws_sw_f = (const float*)((char*)d_ws + 8192);

    kA_stats<<<NBLK, 256, 0, stream>>>(in, book, ws_keys, ws_T, ws_sw);
    kB_write<<<NBLK, 256, 0, stream>>>(book, out, ws_keys, ws_T, ws_sw_f);
}